// Round 4
// baseline (246.406 us; speedup 1.0000x reference)
//
#include <hip/hip_runtime.h>

#define IN_F    4096
#define OUT_F   4096
#define K_DIM   4096
#define NNZ_C   838860
#define BATCH   512
#define SPLITK  4
#define KS      (K_DIM / SPLITK)   // 1024 per split
#define BK      32
#define BM      128
#define BN      128
#define OVF_CAP 131072             // expected dups ~21K; huge margin

typedef short bf16x8 __attribute__((ext_vector_type(8)));
typedef float f32x4  __attribute__((ext_vector_type(4)));

__device__ __forceinline__ unsigned short f2bf(float f) {  // RNE fp32->bf16
    unsigned u = __float_as_uint(f);
    u += 0x7fffu + ((u >> 16) & 1u);
    return (unsigned short)(u >> 16);
}
__device__ __forceinline__ float bf2f(unsigned short h) {
    return __uint_as_float((unsigned)h << 16);
}
__device__ __forceinline__ void gload_lds16(const void* g, void* l) {
    __builtin_amdgcn_global_load_lds(
        (const __attribute__((address_space(1))) unsigned int*)g,
        (__attribute__((address_space(3))) unsigned int*)l, 16, 0, 0);
}

// ---------------------------------------------------------------------------
// K1: x fp32 [512][4096] -> bf16 (same layout; K contiguous = A operand ready)
// ---------------------------------------------------------------------------
__global__ void convert_x(const float* __restrict__ x,
                          unsigned short* __restrict__ xb) {
    int i = blockIdx.x * 256 + threadIdx.x;
    const float4* p = (const float4*)x + (size_t)i * 2;
    float4 a = p[0], b = p[1];
    union { unsigned short h[8]; bf16x8 v; } u;
    u.h[0] = f2bf(a.x); u.h[1] = f2bf(a.y); u.h[2] = f2bf(a.z); u.h[3] = f2bf(a.w);
    u.h[4] = f2bf(b.x); u.h[5] = f2bf(b.y); u.h[6] = f2bf(b.z); u.h[7] = f2bf(b.w);
    ((bf16x8*)xb)[i] = u.v;
}

// ---------------------------------------------------------------------------
// K2a: bitmap-dedup scatter. atomicOr on a 2 MB bitmap (L2-resident) decides
// first-writer in ONE round trip; first writer plain-stores bf16 (fire and
// forget); duplicates (~21K) appended to overflow list for K2b.
// ---------------------------------------------------------------------------
__global__ void scatter_mark(const int* __restrict__ row_idx,
                             const int* __restrict__ col_idx,
                             const float* __restrict__ values,
                             unsigned short* __restrict__ W,
                             unsigned* __restrict__ bitmap,
                             uint2* __restrict__ ovf,
                             int* __restrict__ ovf_cnt) {
    int i = blockIdx.x * 256 + threadIdx.x;
    if (i >= NNZ_C) return;
    unsigned idx = (unsigned)row_idx[i] * K_DIM + (unsigned)col_idx[i];
    unsigned bit = 1u << (idx & 31);
    unsigned old = atomicOr(&bitmap[idx >> 5], bit);
    if (old & bit) {
        int p = atomicAdd(ovf_cnt, 1);
        if (p < OVF_CAP) ovf[p] = make_uint2(idx, __float_as_uint(values[i]));
    } else {
        W[idx] = f2bf(values[i]);   // plain 2-byte store, no return
    }
}

// ---------------------------------------------------------------------------
// K2b: CAS-add the overflow entries (tiny: ~21K expected).
// ---------------------------------------------------------------------------
__global__ void fix_dups(const uint2* __restrict__ ovf,
                         const int* __restrict__ ovf_cnt,
                         unsigned* __restrict__ W32) {
    int i = blockIdx.x * 256 + threadIdx.x;
    int n = min(*ovf_cnt, OVF_CAP);
    if (i >= n) return;
    uint2 e = ovf[i];
    unsigned idx = e.x;
    float v = __uint_as_float(e.y);
    unsigned* wp = &W32[idx >> 1];
    int hi = (int)(idx & 1);
    unsigned old = *wp, assumed;
    do {
        assumed = old;
        unsigned short cur = hi ? (unsigned short)(assumed >> 16)
                                : (unsigned short)(assumed & 0xffffu);
        unsigned short nh = f2bf(bf2f(cur) + v);
        unsigned nw = hi ? ((assumed & 0x0000ffffu) | ((unsigned)nh << 16))
                         : ((assumed & 0xffff0000u) | (unsigned)nh);
        old = atomicCAS(wp, assumed, nw);
    } while (old != assumed);
}

// ---------------------------------------------------------------------------
// K2-fallback: CAS scatter (used only if ws too small for bitmap+overflow).
// ---------------------------------------------------------------------------
__global__ void scatter_cas(const int* __restrict__ row_idx,
                            const int* __restrict__ col_idx,
                            const float* __restrict__ values,
                            unsigned* __restrict__ W32) {
    int i = blockIdx.x * 256 + threadIdx.x;
    if (i >= NNZ_C) return;
    size_t idx = (size_t)row_idx[i] * K_DIM + (size_t)col_idx[i];
    float v = values[i];
    unsigned* wp = &W32[idx >> 1];
    int hi = (int)(idx & 1);
    unsigned old = *wp, assumed;
    do {
        assumed = old;
        unsigned short cur = hi ? (unsigned short)(assumed >> 16)
                                : (unsigned short)(assumed & 0xffffu);
        unsigned short nh = f2bf(bf2f(cur) + v);
        unsigned nw = hi ? ((assumed & 0x0000ffffu) | ((unsigned)nh << 16))
                         : ((assumed & 0xffff0000u) | (unsigned)nh);
        old = atomicCAS(wp, assumed, nw);
    } while (old != assumed);
}

// ---------------------------------------------------------------------------
// K3: bf16 GEMM, B^T layout (m97 128x128xBK32 structure, split-K=4).
// 4 waves in 2x2; each wave = 64x64 via 4x4 grid of 16x16x32 MFMAs.
// Per wave per k-iter: 4 gload_lds16 + 8 ds_read_b128 + 16 MFMA.
// Bias folded into split-0 accumulator init.
// EPI 0: split0 -> out, split s>0 -> parts[s-1].  EPI 1: atomicAdd into out.
// ---------------------------------------------------------------------------
template <int EPI>
__global__ void __launch_bounds__(256)
gemm_bt(const unsigned short* __restrict__ Abf,   // [512][4096] bf16
        const unsigned short* __restrict__ Wbf,   // [4096][4096] bf16
        const float* __restrict__ bias,
        float* __restrict__ out,                  // [512][4096] f32
        float* __restrict__ parts) {              // 3 x [512][4096] f32
    __shared__ __align__(16) unsigned short As[BM * BK];   // 8 KB
    __shared__ __align__(16) unsigned short Bs[BN * BK];   // 8 KB

    const int nt = blockIdx.x, mt = blockIdx.y, s = blockIdx.z;
    const int t = threadIdx.x, w = t >> 6, ln = t & 63;
    const int wm = w & 1, wn = w >> 1;
    const int ks0 = s * KS;

    // staging: wave w stages 16 rows at w*16 and 64+w*16 for both tiles;
    // lane ln: row += ln>>2, byte col = (ln&3)*16 -> lane-linear LDS dst.
    const int srow = w * 16 + (ln >> 2);
    const int scol = (ln & 3) * 8;                 // bf16 elems
    const unsigned short* gA0 = Abf + (size_t)(mt * BM + srow) * K_DIM + ks0 + scol;
    const unsigned short* gA1 = gA0 + (size_t)64 * K_DIM;
    const unsigned short* gB0 = Wbf + (size_t)(nt * BN + srow) * K_DIM + ks0 + scol;
    const unsigned short* gB1 = gB0 + (size_t)64 * K_DIM;
    unsigned short* lA0 = &As[(w * 16) * BK];
    unsigned short* lA1 = &As[(64 + w * 16) * BK];
    unsigned short* lB0 = &Bs[(w * 16) * BK];
    unsigned short* lB1 = &Bs[(64 + w * 16) * BK];

    const int quad = ln >> 4, lanem = ln & 15;
    const unsigned short* rA = &As[(wm * 64 + lanem) * BK + quad * 8];
    const unsigned short* rB = &Bs[(wn * 64 + lanem) * BK + quad * 8];

    float bv[4];
#pragma unroll
    for (int ni = 0; ni < 4; ++ni)
        bv[ni] = bias[nt * BN + wn * 64 + ni * 16 + lanem];

    f32x4 acc[4][4];
#pragma unroll
    for (int mi = 0; mi < 4; ++mi)
#pragma unroll
        for (int ni = 0; ni < 4; ++ni) {
            float iv = (s == 0) ? bv[ni] : 0.f;
            acc[mi][ni] = (f32x4){iv, iv, iv, iv};
        }

    for (int kt = 0; kt < KS / BK; ++kt) {
        __syncthreads();                       // prior iter's LDS reads done
        gload_lds16(gA0 + kt * BK, lA0);
        gload_lds16(gA1 + kt * BK, lA1);
        gload_lds16(gB0 + kt * BK, lB0);
        gload_lds16(gB1 + kt * BK, lB1);
        __syncthreads();                       // staging drained

        bf16x8 af[4], bfr[4];
#pragma unroll
        for (int mi = 0; mi < 4; ++mi) af[mi]  = *(const bf16x8*)(rA + mi * 16 * BK);
#pragma unroll
        for (int ni = 0; ni < 4; ++ni) bfr[ni] = *(const bf16x8*)(rB + ni * 16 * BK);
#pragma unroll
        for (int mi = 0; mi < 4; ++mi)
#pragma unroll
            for (int ni = 0; ni < 4; ++ni)
                acc[mi][ni] = __builtin_amdgcn_mfma_f32_16x16x32_bf16(
                    af[mi], bfr[ni], acc[mi][ni], 0, 0, 0);
    }

    // C/D layout: col = lanem, row = quad*4 + r
    const int row0 = mt * BM + wm * 64 + quad * 4;
    const int col0 = nt * BN + wn * 64 + lanem;
#pragma unroll
    for (int mi = 0; mi < 4; ++mi)
#pragma unroll
        for (int ni = 0; ni < 4; ++ni) {
            int c = col0 + ni * 16;
#pragma unroll
            for (int r = 0; r < 4; ++r) {
                size_t o = (size_t)(row0 + mi * 16 + r) * OUT_F + c;
                if (EPI == 0) {
                    float* dst = (s == 0) ? out
                               : parts + (size_t)(s - 1) * BATCH * OUT_F;
                    dst[o] = acc[mi][ni][r];
                } else {
                    atomicAdd(&out[o], acc[mi][ni][r]);
                }
            }
        }
}

// ---------------------------------------------------------------------------
// K4: out += parts[0..2] (split-K reduction), float4 streams.
// ---------------------------------------------------------------------------
__global__ void reduce_parts(float* __restrict__ out,
                             const float* __restrict__ parts) {
    int i = blockIdx.x * 256 + threadIdx.x;        // 524288 float4s
    const float4* p0 = (const float4*)parts;
    const float4* p1 = p0 + (size_t)BATCH * OUT_F / 4;
    const float4* p2 = p1 + (size_t)BATCH * OUT_F / 4;
    float4 a = ((const float4*)out)[i];
    float4 b = p0[i], c = p1[i], d = p2[i];
    a.x += b.x + c.x + d.x;
    a.y += b.y + c.y + d.y;
    a.z += b.z + c.z + d.z;
    a.w += b.w + c.w + d.w;
    ((float4*)out)[i] = a;
}

// ---------------------------------------------------------------------------
// ws: xb 4.19 | W 33.55 | bitmap 2.10 | ovf_cnt 256B | ovf 1.05 | parts 25.17
//     total ~66.1 MB. Runtime fallbacks if ws is smaller.
// ---------------------------------------------------------------------------
extern "C" void kernel_launch(void* const* d_in, const int* in_sizes, int n_in,
                              void* d_out, int out_size, void* d_ws, size_t ws_size,
                              hipStream_t stream) {
    const float* x       = (const float*)d_in[0];
    const int*   row_idx = (const int*)d_in[1];
    const int*   col_idx = (const int*)d_in[2];
    const float* values  = (const float*)d_in[3];
    const float* bias    = (const float*)d_in[4];
    float*       out     = (float*)d_out;

    size_t off = 0;
    unsigned short* xb = (unsigned short*)((char*)d_ws + off);
    off += (size_t)BATCH * K_DIM * 2;
    unsigned short* W = (unsigned short*)((char*)d_ws + off);
    off += (size_t)OUT_F * K_DIM * 2;
    unsigned* bitmap = (unsigned*)((char*)d_ws + off);
    off += (size_t)OUT_F * K_DIM / 8;              // 2 MB
    int* ovf_cnt = (int*)((char*)d_ws + off);
    off += 256;
    uint2* ovf = (uint2*)((char*)d_ws + off);
    off += (size_t)OVF_CAP * 8;
    size_t need_bitmap = off;
    float* parts = (float*)((char*)d_ws + off);
    off += (size_t)3 * BATCH * OUT_F * 4;
    size_t need_parts = off;

    bool use_bitmap = (ws_size >= need_bitmap);
    bool use_parts  = (ws_size >= need_parts);

    hipMemsetAsync(W, 0, (size_t)OUT_F * K_DIM * 2, stream);
    convert_x<<<1024, 256, 0, stream>>>(x, xb);

    if (use_bitmap) {
        // bitmap + ovf_cnt are contiguous: one memset covers both
        hipMemsetAsync(bitmap, 0, (size_t)OUT_F * K_DIM / 8 + 256, stream);
        scatter_mark<<<(NNZ_C + 255) / 256, 256, 0, stream>>>(
            row_idx, col_idx, values, W, bitmap, ovf, ovf_cnt);
        fix_dups<<<OVF_CAP / 256, 256, 0, stream>>>(ovf, ovf_cnt, (unsigned*)W);
    } else {
        scatter_cas<<<(NNZ_C + 255) / 256, 256, 0, stream>>>(
            row_idx, col_idx, values, (unsigned*)W);
    }

    if (use_parts) {
        gemm_bt<0><<<dim3(OUT_F / BN, BATCH / BM, SPLITK), 256, 0, stream>>>(
            xb, W, bias, out, parts);
        reduce_parts<<<BATCH * OUT_F / 4 / 256, 256, 0, stream>>>(out, parts);
    } else {
        hipMemsetAsync(out, 0, (size_t)BATCH * OUT_F * 4, stream);
        gemm_bt<1><<<dim3(OUT_F / BN, BATCH / BM, SPLITK), 256, 0, stream>>>(
            xb, W, bias, out, nullptr);
    }
}

// Round 5
// 194.046 us; speedup vs baseline: 1.2698x; 1.2698x over previous
//
#include <hip/hip_runtime.h>

#define IN_F    4096
#define OUT_F   4096
#define K_DIM   4096
#define NNZ_C   838860
#define BATCH   512
#define SPLITK  8
#define KS      (K_DIM / SPLITK)   // 512 per split
#define BK      32
#define BM      128
#define BN      128

typedef short bf16x8 __attribute__((ext_vector_type(8)));
typedef float f32x4  __attribute__((ext_vector_type(4)));

__device__ __forceinline__ unsigned short f2bf(float f) {  // RNE fp32->bf16
    unsigned u = __float_as_uint(f);
    u += 0x7fffu + ((u >> 16) & 1u);
    return (unsigned short)(u >> 16);
}
__device__ __forceinline__ void gload_lds16(const void* g, void* l) {
    __builtin_amdgcn_global_load_lds(
        (const __attribute__((address_space(1))) unsigned int*)g,
        (__attribute__((address_space(3))) unsigned int*)l, 16, 0, 0);
}

// ---------------------------------------------------------------------------
// K1: x fp32 [512][4096] -> bf16 (same layout; K contiguous = A operand ready)
// ---------------------------------------------------------------------------
__global__ void convert_x(const float* __restrict__ x,
                          unsigned short* __restrict__ xb) {
    int i = blockIdx.x * 256 + threadIdx.x;
    const float4* p = (const float4*)x + (size_t)i * 2;
    float4 a = p[0], b = p[1];
    union { unsigned short h[8]; bf16x8 v; } u;
    u.h[0] = f2bf(a.x); u.h[1] = f2bf(a.y); u.h[2] = f2bf(a.z); u.h[3] = f2bf(a.w);
    u.h[4] = f2bf(b.x); u.h[5] = f2bf(b.y); u.h[6] = f2bf(b.z); u.h[7] = f2bf(b.w);
    ((bf16x8*)xb)[i] = u.v;
}

// ---------------------------------------------------------------------------
// K2: COO scatter-add via packed-bf16 atomic fadd. ONE fire-and-forget
// instruction per nnz: no return value, no CAS loop, no dedup structures.
// Duplicates add exactly (in bf16). Non-target half adds +0.0 (identity).
// R4 lesson: returning atomics to concentrated lines serialize at the
// coherence point -- this has neither property.
// ---------------------------------------------------------------------------
__global__ void scatter_pk(const int* __restrict__ row_idx,
                           const int* __restrict__ col_idx,
                           const float* __restrict__ values,
                           unsigned short* __restrict__ W) {
    int i = blockIdx.x * 256 + threadIdx.x;
    if (i >= NNZ_C) return;
    unsigned idx = (unsigned)row_idx[i] * K_DIM + (unsigned)col_idx[i];
    unsigned short h = f2bf(values[i]);
    unsigned data = (idx & 1u) ? ((unsigned)h << 16) : (unsigned)h;
    unsigned long long addr = (unsigned long long)(W + (idx & ~1u));
    asm volatile("global_atomic_pk_add_bf16 %0, %1, off"
                 :: "v"(addr), "v"(data) : "memory");
}

// ---------------------------------------------------------------------------
// K3: out[b][:] = bias  (epilogue atomics then accumulate on top)
// ---------------------------------------------------------------------------
__global__ void init_out_bias(const float* __restrict__ bias,
                              float* __restrict__ out) {
    int i = blockIdx.x * 256 + threadIdx.x;          // 524288 float4s
    float4 b = ((const float4*)bias)[i & (OUT_F / 4 - 1)];
    ((float4*)out)[i] = b;
}

// ---------------------------------------------------------------------------
// K4: bf16 GEMM, B^T layout (m97 128x128xBK32 structure), split-K=8 ->
// 1024 blocks for occupancy. Epilogue: returnless atomicAdd f32 into
// bias-initialized out (coalesced 64B segments; no parts/reduce pass).
// ---------------------------------------------------------------------------
__global__ void __launch_bounds__(256)
gemm_bt(const unsigned short* __restrict__ Abf,   // [512][4096] bf16
        const unsigned short* __restrict__ Wbf,   // [4096][4096] bf16
        float* __restrict__ out) {                // [512][4096] f32, bias-filled
    __shared__ __align__(16) unsigned short As[BM * BK];   // 8 KB
    __shared__ __align__(16) unsigned short Bs[BN * BK];   // 8 KB

    const int nt = blockIdx.x, mt = blockIdx.y, s = blockIdx.z;
    const int t = threadIdx.x, w = t >> 6, ln = t & 63;
    const int wm = w & 1, wn = w >> 1;
    const int ks0 = s * KS;

    const int srow = w * 16 + (ln >> 2);
    const int scol = (ln & 3) * 8;
    const unsigned short* gA0 = Abf + (size_t)(mt * BM + srow) * K_DIM + ks0 + scol;
    const unsigned short* gA1 = gA0 + (size_t)64 * K_DIM;
    const unsigned short* gB0 = Wbf + (size_t)(nt * BN + srow) * K_DIM + ks0 + scol;
    const unsigned short* gB1 = gB0 + (size_t)64 * K_DIM;
    unsigned short* lA0 = &As[(w * 16) * BK];
    unsigned short* lA1 = &As[(64 + w * 16) * BK];
    unsigned short* lB0 = &Bs[(w * 16) * BK];
    unsigned short* lB1 = &Bs[(64 + w * 16) * BK];

    const int quad = ln >> 4, lanem = ln & 15;
    const unsigned short* rA = &As[(wm * 64 + lanem) * BK + quad * 8];
    const unsigned short* rB = &Bs[(wn * 64 + lanem) * BK + quad * 8];

    f32x4 acc[4][4];
#pragma unroll
    for (int mi = 0; mi < 4; ++mi)
#pragma unroll
        for (int ni = 0; ni < 4; ++ni)
            acc[mi][ni] = (f32x4){0.f, 0.f, 0.f, 0.f};

    for (int kt = 0; kt < KS / BK; ++kt) {
        __syncthreads();
        gload_lds16(gA0 + kt * BK, lA0);
        gload_lds16(gA1 + kt * BK, lA1);
        gload_lds16(gB0 + kt * BK, lB0);
        gload_lds16(gB1 + kt * BK, lB1);
        __syncthreads();

        bf16x8 af[4], bfr[4];
#pragma unroll
        for (int mi = 0; mi < 4; ++mi) af[mi]  = *(const bf16x8*)(rA + mi * 16 * BK);
#pragma unroll
        for (int ni = 0; ni < 4; ++ni) bfr[ni] = *(const bf16x8*)(rB + ni * 16 * BK);
#pragma unroll
        for (int mi = 0; mi < 4; ++mi)
#pragma unroll
            for (int ni = 0; ni < 4; ++ni)
                acc[mi][ni] = __builtin_amdgcn_mfma_f32_16x16x32_bf16(
                    af[mi], bfr[ni], acc[mi][ni], 0, 0, 0);
    }

    // C/D layout: col = lanem, row = quad*4 + r. Returnless atomicAdd:
    // fire-and-forget, 16 consecutive lanes per 64B segment.
    const int row0 = mt * BM + wm * 64 + quad * 4;
    const int col0 = nt * BN + wn * 64 + lanem;
#pragma unroll
    for (int mi = 0; mi < 4; ++mi)
#pragma unroll
        for (int ni = 0; ni < 4; ++ni) {
            int c = col0 + ni * 16;
#pragma unroll
            for (int r = 0; r < 4; ++r) {
                size_t o = (size_t)(row0 + mi * 16 + r) * OUT_F + c;
                atomicAdd(&out[o], acc[mi][ni][r]);
            }
        }
}

// ---------------------------------------------------------------------------
// ws: xb 4.19 MB | W 33.55 MB  = 37.75 MB total
// ---------------------------------------------------------------------------
extern "C" void kernel_launch(void* const* d_in, const int* in_sizes, int n_in,
                              void* d_out, int out_size, void* d_ws, size_t ws_size,
                              hipStream_t stream) {
    const float* x       = (const float*)d_in[0];
    const int*   row_idx = (const int*)d_in[1];
    const int*   col_idx = (const int*)d_in[2];
    const float* values  = (const float*)d_in[3];
    const float* bias    = (const float*)d_in[4];
    float*       out     = (float*)d_out;

    unsigned short* xb = (unsigned short*)d_ws;
    unsigned short* W  = xb + (size_t)BATCH * K_DIM;

    hipMemsetAsync(W, 0, (size_t)OUT_F * K_DIM * 2, stream);
    convert_x<<<1024, 256, 0, stream>>>(x, xb);
    scatter_pk<<<(NNZ_C + 255) / 256, 256, 0, stream>>>(row_idx, col_idx, values, W);
    init_out_bias<<<2048, 256, 0, stream>>>(bias, out);
    gemm_bt<<<dim3(OUT_F / BN, BATCH / BM, SPLITK), 256, 0, stream>>>(xb, W, out);
}

// Round 6
// 172.390 us; speedup vs baseline: 1.4294x; 1.1256x over previous
//
#include <hip/hip_runtime.h>

#define IN_F    4096
#define OUT_F   4096
#define K_DIM   4096
#define NNZ_C   838860
#define BATCH   512
#define SPLITK  4
#define KS      (K_DIM / SPLITK)   // 1024 per split -> 32 k-iters/block
#define BK      32
#define BM      128
#define BN      128

typedef short bf16x8 __attribute__((ext_vector_type(8)));
typedef float f32x4  __attribute__((ext_vector_type(4)));

__device__ __forceinline__ unsigned short f2bf(float f) {  // RNE fp32->bf16
    unsigned u = __float_as_uint(f);
    u += 0x7fffu + ((u >> 16) & 1u);
    return (unsigned short)(u >> 16);
}
__device__ __forceinline__ void gload_lds16(const void* g, void* l) {
    __builtin_amdgcn_global_load_lds(
        (const __attribute__((address_space(1))) unsigned int*)g,
        (__attribute__((address_space(3))) unsigned int*)l, 16, 0, 0);
}

// ---------------------------------------------------------------------------
// K1: x fp32 [512][4096] -> bf16 (same layout; K contiguous = A operand ready)
// ---------------------------------------------------------------------------
__global__ void convert_x(const float* __restrict__ x,
                          unsigned short* __restrict__ xb) {
    int i = blockIdx.x * 256 + threadIdx.x;
    const float4* p = (const float4*)x + (size_t)i * 2;
    float4 a = p[0], b = p[1];
    union { unsigned short h[8]; bf16x8 v; } u;
    u.h[0] = f2bf(a.x); u.h[1] = f2bf(a.y); u.h[2] = f2bf(a.z); u.h[3] = f2bf(a.w);
    u.h[4] = f2bf(b.x); u.h[5] = f2bf(b.y); u.h[6] = f2bf(b.z); u.h[7] = f2bf(b.w);
    ((bf16x8*)xb)[i] = u.v;
}

// ---------------------------------------------------------------------------
// K2: COO scatter-add via packed-bf16 atomic fadd (fire-and-forget, exact
// duplicate handling, no CAS). R4 lesson: no returning atomics.
// ---------------------------------------------------------------------------
__global__ void scatter_pk(const int* __restrict__ row_idx,
                           const int* __restrict__ col_idx,
                           const float* __restrict__ values,
                           unsigned short* __restrict__ W) {
    int i = blockIdx.x * 256 + threadIdx.x;
    if (i >= NNZ_C) return;
    unsigned idx = (unsigned)row_idx[i] * K_DIM + (unsigned)col_idx[i];
    unsigned short h = f2bf(values[i]);
    unsigned data = (idx & 1u) ? ((unsigned)h << 16) : (unsigned)h;
    unsigned long long addr = (unsigned long long)(W + (idx & ~1u));
    asm volatile("global_atomic_pk_add_bf16 %0, %1, off"
                 :: "v"(addr), "v"(data) : "memory");
}

// ---------------------------------------------------------------------------
// K3: out[b][:] = bias  (epilogue atomics accumulate on top; replaces the
// zero-memset the harness poison forces, so it is free)
// ---------------------------------------------------------------------------
__global__ void init_out_bias(const float* __restrict__ bias,
                              float* __restrict__ out) {
    int i = blockIdx.x * 256 + threadIdx.x;          // 524288 float4s
    float4 b = ((const float4*)bias)[i & (OUT_F / 4 - 1)];
    ((float4*)out)[i] = b;
}

// ---------------------------------------------------------------------------
// K4: bf16 GEMM, B^T layout, 128x128xBK32, split-K=4.
//
// LDS XOR-swizzle (R5: 2.1M bank conflicts = 8-way on ds_read_b128 because
// 64B row stride aliases all even rows to banks 0-15, odd to 16-31):
//   physical 16B chunk p of row r holds logical chunk p ^ ((r>>1)&3).
//   Staged via per-lane *global* source swizzle (LDS dst is HW lane-linear);
//   reader picks physical chunk q ^ ((lanem>>1)&3). Each 16-lane quad-group
//   then covers all 32 banks exactly 2x = conflict-free (m136).
//   Swizzle depends only on lane id: row bases (w*16, +64, wm*64) are all
//   multiples of 8 rows, so (r>>1)&3 == (r_rel>>1)&3.
// ---------------------------------------------------------------------------
__global__ void __launch_bounds__(256)
gemm_bt(const unsigned short* __restrict__ Abf,   // [512][4096] bf16
        const unsigned short* __restrict__ Wbf,   // [4096][4096] bf16
        float* __restrict__ out) {                // [512][4096] f32, bias-filled
    __shared__ __align__(16) unsigned short As[BM * BK];   // 8 KB
    __shared__ __align__(16) unsigned short Bs[BN * BK];   // 8 KB

    const int nt = blockIdx.x, mt = blockIdx.y, s = blockIdx.z;
    const int t = threadIdx.x, w = t >> 6, ln = t & 63;
    const int wm = w & 1, wn = w >> 1;
    const int ks0 = s * KS;

    // staging: lane ln -> LDS row (ln>>2), physical chunk (ln&3);
    // global source = logical chunk (ln&3) ^ ((ln>>3)&3)
    const int srow = w * 16 + (ln >> 2);
    const int scol = (((ln & 3) ^ ((ln >> 3) & 3)) * 8);   // bf16 elems
    const unsigned short* gA0 = Abf + (size_t)(mt * BM + srow) * K_DIM + ks0 + scol;
    const unsigned short* gA1 = gA0 + (size_t)64 * K_DIM;
    const unsigned short* gB0 = Wbf + (size_t)(nt * BN + srow) * K_DIM + ks0 + scol;
    const unsigned short* gB1 = gB0 + (size_t)64 * K_DIM;
    unsigned short* lA0 = &As[(w * 16) * BK];
    unsigned short* lA1 = &As[(64 + w * 16) * BK];
    unsigned short* lB0 = &Bs[(w * 16) * BK];
    unsigned short* lB1 = &Bs[(64 + w * 16) * BK];

    // fragment read: logical quad q -> physical chunk q ^ ((lanem>>1)&3)
    const int quad = ln >> 4, lanem = ln & 15;
    const int rsw = (quad ^ ((lanem >> 1) & 3)) * 8;
    const unsigned short* rA = &As[(wm * 64 + lanem) * BK + rsw];
    const unsigned short* rB = &Bs[(wn * 64 + lanem) * BK + rsw];

    f32x4 acc[4][4];
#pragma unroll
    for (int mi = 0; mi < 4; ++mi)
#pragma unroll
        for (int ni = 0; ni < 4; ++ni)
            acc[mi][ni] = (f32x4){0.f, 0.f, 0.f, 0.f};

    for (int kt = 0; kt < KS / BK; ++kt) {
        __syncthreads();
        gload_lds16(gA0 + kt * BK, lA0);
        gload_lds16(gA1 + kt * BK, lA1);
        gload_lds16(gB0 + kt * BK, lB0);
        gload_lds16(gB1 + kt * BK, lB1);
        __syncthreads();

        bf16x8 af[4], bfr[4];
#pragma unroll
        for (int mi = 0; mi < 4; ++mi) af[mi]  = *(const bf16x8*)(rA + mi * 16 * BK);
#pragma unroll
        for (int ni = 0; ni < 4; ++ni) bfr[ni] = *(const bf16x8*)(rB + ni * 16 * BK);
#pragma unroll
        for (int mi = 0; mi < 4; ++mi)
#pragma unroll
            for (int ni = 0; ni < 4; ++ni)
                acc[mi][ni] = __builtin_amdgcn_mfma_f32_16x16x32_bf16(
                    af[mi], bfr[ni], acc[mi][ni], 0, 0, 0);
    }

    // C/D layout: col = lanem, row = quad*4 + r. Returnless atomicAdd,
    // 16 consecutive lanes per 64B segment.
    const int row0 = mt * BM + wm * 64 + quad * 4;
    const int col0 = nt * BN + wn * 64 + lanem;
#pragma unroll
    for (int mi = 0; mi < 4; ++mi)
#pragma unroll
        for (int ni = 0; ni < 4; ++ni) {
            int c = col0 + ni * 16;
#pragma unroll
            for (int r = 0; r < 4; ++r) {
                size_t o = (size_t)(row0 + mi * 16 + r) * OUT_F + c;
                atomicAdd(&out[o], acc[mi][ni][r]);
            }
        }
}

// ---------------------------------------------------------------------------
// ws: xb 4.19 MB | W 33.55 MB  = 37.75 MB total
// ---------------------------------------------------------------------------
extern "C" void kernel_launch(void* const* d_in, const int* in_sizes, int n_in,
                              void* d_out, int out_size, void* d_ws, size_t ws_size,
                              hipStream_t stream) {
    const float* x       = (const float*)d_in[0];
    const int*   row_idx = (const int*)d_in[1];
    const int*   col_idx = (const int*)d_in[2];
    const float* values  = (const float*)d_in[3];
    const float* bias    = (const float*)d_in[4];
    float*       out     = (float*)d_out;

    unsigned short* xb = (unsigned short*)d_ws;
    unsigned short* W  = xb + (size_t)BATCH * K_DIM;

    hipMemsetAsync(W, 0, (size_t)OUT_F * K_DIM * 2, stream);
    convert_x<<<1024, 256, 0, stream>>>(x, xb);
    scatter_pk<<<(NNZ_C + 255) / 256, 256, 0, stream>>>(row_idx, col_idx, values, W);
    init_out_bias<<<2048, 256, 0, stream>>>(bias, out);
    gemm_bt<<<dim3(OUT_F / BN, BATCH / BM, SPLITK), 256, 0, stream>>>(xb, W, out);
}